// Round 7
// baseline (131.726 us; speedup 1.0000x reference)
//
#include <hip/hip_runtime.h>

#define T_SEQ 1024
#define C_DIM 512
#define H_HEADS 8
#define HDIM 64
#define B_BATCH 4
#define M_ROWS (B_BATCH * T_SEQ)   // 4096

typedef __attribute__((ext_vector_type(8))) short short8;
typedef __attribute__((ext_vector_type(4))) float f32x4;

__device__ __forceinline__ unsigned short f2bf(float f) {
    unsigned u = __builtin_bit_cast(unsigned, f);
    u += 0x7FFFu + ((u >> 16) & 1u);   // round-to-nearest-even
    return (unsigned short)(u >> 16);
}

__device__ __forceinline__ float bf2f(unsigned short u) {
    return __builtin_bit_cast(float, (unsigned)u << 16);
}

// async global->LDS, 16B per lane; LDS dest = uniform base + lane*16
__device__ __forceinline__ void gload_lds16(const unsigned short* g, unsigned short* l) {
    __builtin_amdgcn_global_load_lds(
        (const __attribute__((address_space(1))) unsigned int*)(const void*)g,
        (__attribute__((address_space(3))) unsigned int*)(void*)l, 16, 0, 0);
}

// ---------------------------------------------------------------------------
// Kernel 1: one-shot cast of x + 4 weight matrices to bf16 (r4/r5: fusing the
// cast into GEMM staging costs ~196 MB of per-block fp32 re-reads — never).
// ---------------------------------------------------------------------------
__global__ __launch_bounds__(256) void cast_all(
    const float* __restrict__ x,
    const float* __restrict__ wq, const float* __restrict__ wk,
    const float* __restrict__ wv, const float* __restrict__ wp,
    unsigned short* __restrict__ xb,
    unsigned short* __restrict__ wqb, unsigned short* __restrict__ wkb,
    unsigned short* __restrict__ wvb, unsigned short* __restrict__ wpb)
{
    const long NX = (long)M_ROWS * C_DIM;
    const long NW = (long)C_DIM * C_DIM;
    long i4 = (long)blockIdx.x * blockDim.x + threadIdx.x;
    long base = i4 * 4;
    const float* src; unsigned short* dst; long off;
    if (base < NX) { src = x; dst = xb; off = base; }
    else {
        long r = base - NX;
        int w = (int)(r >> 18);
        off = r & (NW - 1);
        switch (w) {
            case 0:  src = wq; dst = wqb; break;
            case 1:  src = wk; dst = wkb; break;
            case 2:  src = wv; dst = wvb; break;
            default: src = wp; dst = wpb; break;
        }
    }
    float4 v = *(const float4*)(src + off);
    ushort4 o;
    o.x = f2bf(v.x); o.y = f2bf(v.y); o.z = f2bf(v.z); o.w = f2bf(v.w);
    *(ushort4*)(dst + off) = o;
}

// ---------------------------------------------------------------------------
// GEMM, BM=128 x BN=64 tile (occupancy-balanced: qkv 768 blocks = 3/CU exact,
// out 256 blocks = 1/CU exact).
// r12 (frozen): T4 counted-vmcnt pipeline, dbuf LDS 48 KB, XOR chunk swizzle.
// mode 0: bf16 (B,H,T,HD); mode 1: bf16 (B,H,HD,T) via swapped MFMA operands;
// mode 2: fp32 M x N.
// ---------------------------------------------------------------------------
__device__ __forceinline__ void gemm_body(
    const unsigned short* __restrict__ A,
    const unsigned short* __restrict__ W,
    const float* __restrict__ bias,
    unsigned short* __restrict__ Obf,
    float* __restrict__ Of,
    int mode)
{
    __shared__ __align__(16) unsigned short Atile[2][128 * 64];
    __shared__ __align__(16) unsigned short Btile[2][64 * 64];

    const int tid  = threadIdx.x;
    const int w    = tid >> 6;
    const int lane = tid & 63;
    const int quad = lane >> 4;
    const int l16  = lane & 15;
    const int m0   = blockIdx.x * 128;
    const int n0   = blockIdx.y * 64;

    f32x4 acc[2][4] = {};

    const int lr = lane >> 3;
    const int lc = lane & 7;

    auto stage = [&](int buf, int kk) {
        for (int i = 0; i < 4; ++i) {
            int r0 = 32 * w + 8 * i;
            int r  = r0 + lr;
            int c  = lc ^ (r & 7);      // XOR swizzle
            gload_lds16(&A[(long)(m0 + r) * 512 + kk + c * 8], &Atile[buf][r0 * 64]);
        }
        for (int i = 0; i < 2; ++i) {
            int r0 = 16 * w + 8 * i;
            int r  = r0 + lr;
            int c  = lc ^ (r & 7);
            gload_lds16(&W[(long)(n0 + r) * 512 + kk + c * 8], &Btile[buf][r0 * 64]);
        }
    };

    stage(0, 0);

    #pragma unroll
    for (int k0 = 0; k0 < 512; k0 += 64) {
        const int cur = (k0 >> 6) & 1;
        if (k0 + 64 < 512) {
            __builtin_amdgcn_sched_barrier(0);
            stage(cur ^ 1, k0 + 64);
            asm volatile("s_waitcnt vmcnt(6)" ::: "memory");
        } else {
            asm volatile("s_waitcnt vmcnt(0)" ::: "memory");
        }
        __builtin_amdgcn_s_barrier();
        __builtin_amdgcn_sched_barrier(0);

        for (int st = 0; st < 2; ++st) {
            const int pc = ((4 * st + quad) ^ (l16 & 7)) * 8;
            short8 af[2], bf[4];
            for (int i = 0; i < 2; ++i)
                af[i] = *(const short8*)&Atile[cur][(32 * w + 16 * i + l16) * 64 + pc];
            for (int j = 0; j < 4; ++j)
                bf[j] = *(const short8*)&Btile[cur][(16 * j + l16) * 64 + pc];
            for (int i = 0; i < 2; ++i)
                for (int j = 0; j < 4; ++j)
                    acc[i][j] = (mode == 1)
                        ? __builtin_amdgcn_mfma_f32_16x16x32_bf16(bf[j], af[i], acc[i][j], 0, 0, 0)
                        : __builtin_amdgcn_mfma_f32_16x16x32_bf16(af[i], bf[j], acc[i][j], 0, 0, 0);
        }

        __builtin_amdgcn_sched_barrier(0);
        __builtin_amdgcn_s_barrier();
    }

    if (mode == 1) {
        for (int j = 0; j < 4; ++j) {
            for (int reg = 0; reg < 4; ++reg) {
                int n = n0 + 16 * j + 4 * quad + reg;
                int h = n >> 6, hd = n & 63;
                float bv = bias[n];
                for (int i = 0; i < 2; ++i) {
                    int t = m0 + 32 * w + 16 * i + l16;
                    int b = t >> 10, tl = t & 1023;
                    Obf[(((long)(b * H_HEADS + h)) * HDIM + hd) * T_SEQ + tl] =
                        f2bf(acc[i][j][reg] + bv);
                }
            }
        }
    } else {
        for (int j = 0; j < 4; ++j) {
            int col = n0 + 16 * j + l16;
            float bv = bias[col];
            for (int i = 0; i < 2; ++i) {
                for (int reg = 0; reg < 4; ++reg) {
                    int row = m0 + 32 * w + 16 * i + 4 * quad + reg;
                    float v = acc[i][j][reg] + bv;
                    if (mode == 2) {
                        Of[(long)row * 512 + col] = v;
                    } else {
                        int b = row >> 10, t = row & 1023;
                        int h = col >> 6,  hd = col & 63;
                        Obf[(((long)(b * H_HEADS + h)) * T_SEQ + t) * HDIM + hd] = f2bf(v);
                    }
                }
            }
        }
    }
}

__global__ __launch_bounds__(256) void gemm_qkv(
    const unsigned short* __restrict__ A,
    const unsigned short* __restrict__ Wq, const unsigned short* __restrict__ Wk,
    const unsigned short* __restrict__ Wv,
    const float* __restrict__ bq, const float* __restrict__ bk, const float* __restrict__ bv,
    unsigned short* __restrict__ Q, unsigned short* __restrict__ K,
    unsigned short* __restrict__ V)
{
    const unsigned short* W; const float* b; unsigned short* O; int mode;
    if (blockIdx.z == 0)      { W = Wq; b = bq; O = Q; mode = 0; }
    else if (blockIdx.z == 1) { W = Wk; b = bk; O = K; mode = 0; }
    else                      { W = Wv; b = bv; O = V; mode = 1; }
    gemm_body(A, W, b, O, nullptr, mode);
}

__global__ __launch_bounds__(256) void gemm_out_k(
    const unsigned short* __restrict__ A, const unsigned short* __restrict__ W,
    const float* __restrict__ bias, float* __restrict__ O)
{
    gemm_body(A, W, bias, nullptr, O, 2);
}

// ---------------------------------------------------------------------------
// Kernel 3: NO-SPLIT paired flash attention (r17).
// Mechanism: causal q-block j costs j+1 kt-tiles (1..16). Pairing j with 15-j
// gives every block exactly 17 tiles — perfect static balance WITHOUT split-K.
// Eliminates: attn_combine dispatch + gap, Opart/lpart round-trip (~25 MB),
// and the partial-normalization pass. Grid (bh=32, pair=8) = 256 blocks =
// 1/CU, all resident at t=0, identical durations; XCD = bh%8 keeps each bh's
// K/V (512 KB) in one L2 (1 MB/XCD total).
// Occupancy is 1 wave/SIMD, so staging latency is hidden the gemm_body way:
// counted-vmcnt dbuf — stage next tile's 4 gload_lds into buf^1, vmcnt(4),
// barrier, compute, barrier. Both phases' Q-fragments are hoisted before the
// loop so no stray VMEM perturbs the vmcnt count at the phase boundary.
// Per-tile compute is the proven r13/r15 structure: swapped QK^T (lane holds
// keys for q-row l16), packed ds_write_b64 P, compile-time column mask,
// setprio around MFMA. Normalization in-register: row-sum L lives at lane
// l16 == row; oacc rows are 4*quad+reg -> redistribute via __shfl(lsum, row).
// r14 POST-MORTEM still applies: no cross-block atomics, ever.
// ---------------------------------------------------------------------------
__global__ __launch_bounds__(256) void attn_fused(
    const unsigned short* __restrict__ Q, const unsigned short* __restrict__ K,
    const unsigned short* __restrict__ Vt, const float* __restrict__ attn_bias,
    unsigned short* __restrict__ Y)
{
    __shared__ __align__(16) unsigned short Kl[2][64 * 64];  // [key][hd]
    __shared__ __align__(16) unsigned short Vl[2][64 * 64];  // [hd][key]
    __shared__ __align__(16) unsigned short Pl[4][16 * 72];  // [q(16)][key+pad]
    __shared__ float biasl[8][64];

    const int tid  = threadIdx.x;
    const int w    = tid >> 6;
    const int lane = tid & 63;
    const int quad = lane >> 4;
    const int l16  = lane & 15;
    const int lr   = lane >> 3;
    const int lc   = lane & 7;
    const int bh   = blockIdx.x;
    const int pj   = blockIdx.y;            // 0..7
    const int h    = bh & 7;
    const int b    = bh >> 3;

    const int q0A = pj * 64;                // phase A: biased, tiles 0..pj
    const int q0B = (15 - pj) * 64;         // phase B: unbiased, tiles 0..15-pj
    const int nA  = pj + 1;
    const int nT  = 17;                     // nA + (16 - pj)

    // phase A bias panel (q0A < 512 always; causal => keys < 512 too)
    for (int i = tid; i < 512; i += 256) {
        int nq = (q0A >> 3) + (i >> 6);
        biasl[i >> 6][i & 63] = attn_bias[h * 4096 + nq * 64 + (i & 63)];
    }

    const unsigned short* Qbh = Q  + (long)bh * T_SEQ * HDIM;
    const unsigned short* Kbh = K  + (long)bh * T_SEQ * HDIM;
    const unsigned short* Vbh = Vt + (long)bh * HDIM * T_SEQ;   // [hd][t]

    // hoist BOTH phases' Q fragments (keeps the loop free of extra VMEM)
    const int qrowA = q0A + 16 * w + l16;
    const int qrowB = q0B + 16 * w + l16;
    short8 qfA0 = *(const short8*)&Qbh[(long)qrowA * HDIM + 8 * quad];
    short8 qfA1 = *(const short8*)&Qbh[(long)qrowA * HDIM + 32 + 8 * quad];
    short8 qfB0 = *(const short8*)&Qbh[(long)qrowB * HDIM + 8 * quad];
    short8 qfB1 = *(const short8*)&Qbh[(long)qrowB * HDIM + 32 + 8 * quad];

    // 4 gload_lds16 per thread per tile
    auto stage = [&](int buf, int k0) {
        for (int i2 = 0; i2 < 2; ++i2) {
            int r0 = 16 * w + 8 * i2;
            int r  = r0 + lr;
            int c  = lc ^ (r & 7);
            gload_lds16(&Kbh[(long)(k0 + r) * HDIM + c * 8], &Kl[buf][r0 * 64]);
            gload_lds16(&Vbh[(long)r * T_SEQ + k0 + c * 8], &Vl[buf][r0 * 64]);
        }
    };

    const int brow2 = 2 * w + (l16 >> 3);

    // working phase state
    short8 qf0 = qfA0, qf1 = qfA1;
    int qrow = qrowA, q0c = q0A;
    bool phB = false;
    f32x4 oacc[4] = {};
    float lsum = 0.f;

    stage(0, 0);    // tile t=0 (phase A, kt=0)

    for (int t = 0; t < nT; ++t) {
        const int cur = t & 1;
        if (t == nA) {              // phase switch (uniform branch)
            qf0 = qfB0; qf1 = qfB1; qrow = qrowB; q0c = q0B; phB = true;
            for (int ct = 0; ct < 4; ++ct) oacc[ct] = f32x4{};
            lsum = 0.f;
        }
        const int kt = phB ? (t - nA) : t;
        const int k0 = kt * 64;

        if (t + 1 < nT) {
            __builtin_amdgcn_sched_barrier(0);
            const int t2 = t + 1;
            const int k0n = ((t2 < nA) ? t2 : (t2 - nA)) * 64;
            stage(cur ^ 1, k0n);
            asm volatile("s_waitcnt vmcnt(4)" ::: "memory");
        } else {
            asm volatile("s_waitcnt vmcnt(0)" ::: "memory");
        }
        __builtin_amdgcn_s_barrier();        // tile t resident, biasl ready
        __builtin_amdgcn_sched_barrier(0);

        // S^T = K Q^T (swapped): s[ct][reg] = S[key=16ct+4quad+reg][q=l16]
        f32x4 s[4] = {};
        __builtin_amdgcn_s_setprio(1);
        for (int st = 0; st < 2; ++st) {
            const int pc = ((4 * st + quad) ^ (l16 & 7)) * 8;
            short8 qf = st ? qf1 : qf0;
            for (int ct = 0; ct < 4; ++ct) {
                short8 kf = *(const short8*)&Kl[cur][(16 * ct + l16) * 64 + pc];
                s[ct] = __builtin_amdgcn_mfma_f32_16x16x32_bf16(kf, qf, s[ct], 0, 0, 0);
            }
        }
        __builtin_amdgcn_s_setprio(0);

        // P = exp(S*scale + bias), masking; keys lane-local -> ds_write_b64
        const bool diag = (t == nA - 1) || (t == nT - 1);   // phase-end tiles
        #pragma unroll
        for (int ct = 0; ct < 4; ++ct) {
            const int kbase = k0 + 16 * ct + 4 * quad;
            float bval = !phB ? biasl[brow2][(k0 >> 3) + 2 * ct + (quad >> 1)] : 0.f;
            float pv[4];
            #pragma unroll
            for (int reg = 0; reg < 4; ++reg) {
                float v = fmaf(s[ct][reg], 0.125f, bval);
                bool keep = !(quad == 3 && reg == 3);   // key%16==15 column mask
                if (diag) keep = keep && (kbase + reg <= qrow);
                float p = keep ? __expf(v) : 0.f;
                lsum += p;
                pv[reg] = p;
            }
            uint2 d;
            d.x = (unsigned)f2bf(pv[0]) | ((unsigned)f2bf(pv[1]) << 16);
            d.y = (unsigned)f2bf(pv[2]) | ((unsigned)f2bf(pv[3]) << 16);
            *(uint2*)&Pl[w][l16 * 72 + 16 * ct + 4 * quad] = d;
        }

        // O += P V (Pl is wave-private; lgkmcnt orders within-wave RAW)
        __builtin_amdgcn_s_setprio(1);
        for (int st = 0; st < 2; ++st) {
            const int pc = ((4 * st + quad) ^ (l16 & 7)) * 8;
            short8 af = *(const short8*)&Pl[w][l16 * 72 + 32 * st + 8 * quad];
            for (int ct = 0; ct < 4; ++ct) {
                short8 vf = *(const short8*)&Vl[cur][(16 * ct + l16) * 64 + pc];
                oacc[ct] = __builtin_amdgcn_mfma_f32_16x16x32_bf16(af, vf, oacc[ct], 0, 0, 0);
            }
        }
        __builtin_amdgcn_s_setprio(0);

        __builtin_amdgcn_sched_barrier(0);   // pin LDS reads above
        __builtin_amdgcn_s_barrier();        // buf[cur] free for next overwrite

        if (diag) {
            // finish this phase: reduce row-sums across quads, normalize, write
            float ls = lsum;
            ls += __shfl_xor(ls, 16);
            ls += __shfl_xor(ls, 32);        // all lanes: L of q-row l16
            float linv[4];
            #pragma unroll
            for (int reg = 0; reg < 4; ++reg)
                linv[reg] = 1.f / __shfl(ls, 4 * quad + reg);
            #pragma unroll
            for (int ct = 0; ct < 4; ++ct)
                #pragma unroll
                for (int reg = 0; reg < 4; ++reg) {
                    int q = q0c + 16 * w + 4 * quad + reg;
                    Y[((long)b * T_SEQ + q) * C_DIM + h * HDIM + 16 * ct + l16] =
                        f2bf(oacc[ct][reg] * linv[reg]);
                }
        }
    }
}

// ---------------------------------------------------------------------------
extern "C" void kernel_launch(void* const* d_in, const int* in_sizes, int n_in,
                              void* d_out, int out_size, void* d_ws, size_t ws_size,
                              hipStream_t stream)
{
    const float* x         = (const float*)d_in[0];
    const float* attn_bias = (const float*)d_in[1];
    const float* Wq = (const float*)d_in[2]; const float* bq = (const float*)d_in[3];
    const float* Wk = (const float*)d_in[4]; const float* bk = (const float*)d_in[5];
    const float* Wv = (const float*)d_in[6]; const float* bv = (const float*)d_in[7];
    const float* Wp = (const float*)d_in[8]; const float* bp = (const float*)d_in[9];
    float* out = (float*)d_out;

    const long NX = (long)M_ROWS * C_DIM;    // 2,097,152
    const long NW = (long)C_DIM * C_DIM;     // 262,144

    unsigned short* xb  = (unsigned short*)d_ws;
    unsigned short* wqb = xb  + NX;
    unsigned short* wkb = wqb + NW;
    unsigned short* wvb = wkb + NW;
    unsigned short* wpb = wvb + NW;
    unsigned short* Qb  = wpb + NW;
    unsigned short* Kb  = Qb  + NX;
    unsigned short* Vtb = Kb  + NX;          // transposed (B,H,HD,T)
    unsigned short* Yb  = Vtb + NX;

    long n4 = (NX + 4 * NW) / 4;
    cast_all<<<dim3((unsigned)(n4 / 256)), 256, 0, stream>>>(
        x, Wq, Wk, Wv, Wp, xb, wqb, wkb, wvb, wpb);

    gemm_qkv<<<dim3(M_ROWS / 128, C_DIM / 64, 3), 256, 0, stream>>>(
        xb, wqb, wkb, wvb, bq, bk, bv, Qb, Kb, Vtb);

    attn_fused<<<dim3(B_BATCH * H_HEADS, 8), 256, 0, stream>>>(
        Qb, Kb, Vtb, attn_bias, Yb);

    gemm_out_k<<<dim3(M_ROWS / 128, C_DIM / 64), 256, 0, stream>>>(
        Yb, wpb, bp, out);
}

// Round 8
// 121.941 us; speedup vs baseline: 1.0802x; 1.0802x over previous
//
#include <hip/hip_runtime.h>

#define T_SEQ 1024
#define C_DIM 512
#define H_HEADS 8
#define HDIM 64
#define B_BATCH 4
#define M_ROWS (B_BATCH * T_SEQ)   // 4096
#define NSPLIT_TOT 40              // sum over bx of ceil((bx+1)/4)
#define PSTR 68                    // Pl row stride (r18: 72->68, 27.1KB -> 6 blocks/CU)

typedef __attribute__((ext_vector_type(8))) short short8;
typedef __attribute__((ext_vector_type(4))) float f32x4;

__device__ __forceinline__ unsigned short f2bf(float f) {
    unsigned u = __builtin_bit_cast(unsigned, f);
    u += 0x7FFFu + ((u >> 16) & 1u);   // round-to-nearest-even
    return (unsigned short)(u >> 16);
}

__device__ __forceinline__ float bf2f(unsigned short u) {
    return __builtin_bit_cast(float, (unsigned)u << 16);
}

// async global->LDS, 16B per lane; LDS dest = uniform base + lane*16
__device__ __forceinline__ void gload_lds16(const unsigned short* g, unsigned short* l) {
    __builtin_amdgcn_global_load_lds(
        (const __attribute__((address_space(1))) unsigned int*)(const void*)g,
        (__attribute__((address_space(3))) unsigned int*)(void*)l, 16, 0, 0);
}

__device__ __constant__ unsigned char BX_OF[NSPLIT_TOT] =
    {0,1,2,3,4,4,5,5,6,6,7,7,8,8,8,9,9,9,10,10,10,11,11,11,
     12,12,12,12,13,13,13,13,14,14,14,14,15,15,15,15};
__device__ __constant__ unsigned char SP_OF[NSPLIT_TOT] =
    {0,0,0,0,0,1,0,1,0,1,0,1,0,1,2,0,1,2,0,1,2,0,1,2,
     0,1,2,3,0,1,2,3,0,1,2,3,0,1,2,3};
__device__ __constant__ unsigned char CUM_OF[16] =
    {0,1,2,3,4,6,8,10,12,15,18,21,24,28,32,36};

// ---------------------------------------------------------------------------
// Kernel 1: one-shot cast of x + 4 weight matrices to bf16 (r4/r5: fusing the
// cast into GEMM staging costs ~196 MB of per-block fp32 re-reads — never).
// ---------------------------------------------------------------------------
__global__ __launch_bounds__(256) void cast_all(
    const float* __restrict__ x,
    const float* __restrict__ wq, const float* __restrict__ wk,
    const float* __restrict__ wv, const float* __restrict__ wp,
    unsigned short* __restrict__ xb,
    unsigned short* __restrict__ wqb, unsigned short* __restrict__ wkb,
    unsigned short* __restrict__ wvb, unsigned short* __restrict__ wpb)
{
    const long NX = (long)M_ROWS * C_DIM;
    const long NW = (long)C_DIM * C_DIM;
    long i4 = (long)blockIdx.x * blockDim.x + threadIdx.x;
    long base = i4 * 4;
    const float* src; unsigned short* dst; long off;
    if (base < NX) { src = x; dst = xb; off = base; }
    else {
        long r = base - NX;
        int w = (int)(r >> 18);
        off = r & (NW - 1);
        switch (w) {
            case 0:  src = wq; dst = wqb; break;
            case 1:  src = wk; dst = wkb; break;
            case 2:  src = wv; dst = wvb; break;
            default: src = wp; dst = wpb; break;
        }
    }
    float4 v = *(const float4*)(src + off);
    ushort4 o;
    o.x = f2bf(v.x); o.y = f2bf(v.y); o.z = f2bf(v.z); o.w = f2bf(v.w);
    *(ushort4*)(dst + off) = o;
}

// ---------------------------------------------------------------------------
// GEMM, BM=128 x BN=64 tile (occupancy-balanced: qkv 768 blocks = 3/CU exact,
// out 256 blocks = 1/CU exact).
// r12 (frozen): T4 counted-vmcnt pipeline, dbuf LDS 48 KB, XOR chunk swizzle.
// mode 0: bf16 (B,H,T,HD); mode 1: bf16 (B,H,HD,T) via swapped MFMA operands;
// mode 2: fp32 M x N.
// ---------------------------------------------------------------------------
__device__ __forceinline__ void gemm_body(
    const unsigned short* __restrict__ A,
    const unsigned short* __restrict__ W,
    const float* __restrict__ bias,
    unsigned short* __restrict__ Obf,
    float* __restrict__ Of,
    int mode)
{
    __shared__ __align__(16) unsigned short Atile[2][128 * 64];
    __shared__ __align__(16) unsigned short Btile[2][64 * 64];

    const int tid  = threadIdx.x;
    const int w    = tid >> 6;
    const int lane = tid & 63;
    const int quad = lane >> 4;
    const int l16  = lane & 15;
    const int m0   = blockIdx.x * 128;
    const int n0   = blockIdx.y * 64;

    f32x4 acc[2][4] = {};

    const int lr = lane >> 3;
    const int lc = lane & 7;

    auto stage = [&](int buf, int kk) {
        for (int i = 0; i < 4; ++i) {
            int r0 = 32 * w + 8 * i;
            int r  = r0 + lr;
            int c  = lc ^ (r & 7);      // XOR swizzle
            gload_lds16(&A[(long)(m0 + r) * 512 + kk + c * 8], &Atile[buf][r0 * 64]);
        }
        for (int i = 0; i < 2; ++i) {
            int r0 = 16 * w + 8 * i;
            int r  = r0 + lr;
            int c  = lc ^ (r & 7);
            gload_lds16(&W[(long)(n0 + r) * 512 + kk + c * 8], &Btile[buf][r0 * 64]);
        }
    };

    stage(0, 0);

    #pragma unroll
    for (int k0 = 0; k0 < 512; k0 += 64) {
        const int cur = (k0 >> 6) & 1;
        if (k0 + 64 < 512) {
            __builtin_amdgcn_sched_barrier(0);
            stage(cur ^ 1, k0 + 64);
            asm volatile("s_waitcnt vmcnt(6)" ::: "memory");
        } else {
            asm volatile("s_waitcnt vmcnt(0)" ::: "memory");
        }
        __builtin_amdgcn_s_barrier();
        __builtin_amdgcn_sched_barrier(0);

        for (int st = 0; st < 2; ++st) {
            const int pc = ((4 * st + quad) ^ (l16 & 7)) * 8;
            short8 af[2], bf[4];
            for (int i = 0; i < 2; ++i)
                af[i] = *(const short8*)&Atile[cur][(32 * w + 16 * i + l16) * 64 + pc];
            for (int j = 0; j < 4; ++j)
                bf[j] = *(const short8*)&Btile[cur][(16 * j + l16) * 64 + pc];
            for (int i = 0; i < 2; ++i)
                for (int j = 0; j < 4; ++j)
                    acc[i][j] = (mode == 1)
                        ? __builtin_amdgcn_mfma_f32_16x16x32_bf16(bf[j], af[i], acc[i][j], 0, 0, 0)
                        : __builtin_amdgcn_mfma_f32_16x16x32_bf16(af[i], bf[j], acc[i][j], 0, 0, 0);
        }

        __builtin_amdgcn_sched_barrier(0);
        __builtin_amdgcn_s_barrier();
    }

    if (mode == 1) {
        for (int j = 0; j < 4; ++j) {
            for (int reg = 0; reg < 4; ++reg) {
                int n = n0 + 16 * j + 4 * quad + reg;
                int h = n >> 6, hd = n & 63;
                float bv = bias[n];
                for (int i = 0; i < 2; ++i) {
                    int t = m0 + 32 * w + 16 * i + l16;
                    int b = t >> 10, tl = t & 1023;
                    Obf[(((long)(b * H_HEADS + h)) * HDIM + hd) * T_SEQ + tl] =
                        f2bf(acc[i][j][reg] + bv);
                }
            }
        }
    } else {
        for (int j = 0; j < 4; ++j) {
            int col = n0 + 16 * j + l16;
            float bv = bias[col];
            for (int i = 0; i < 2; ++i) {
                for (int reg = 0; reg < 4; ++reg) {
                    int row = m0 + 32 * w + 16 * i + 4 * quad + reg;
                    float v = acc[i][j][reg] + bv;
                    if (mode == 2) {
                        Of[(long)row * 512 + col] = v;
                    } else {
                        int b = row >> 10, t = row & 1023;
                        int h = col >> 6,  hd = col & 63;
                        Obf[(((long)(b * H_HEADS + h)) * T_SEQ + t) * HDIM + hd] = f2bf(v);
                    }
                }
            }
        }
    }
}

__global__ __launch_bounds__(256) void gemm_qkv(
    const unsigned short* __restrict__ A,
    const unsigned short* __restrict__ Wq, const unsigned short* __restrict__ Wk,
    const unsigned short* __restrict__ Wv,
    const float* __restrict__ bq, const float* __restrict__ bk, const float* __restrict__ bv,
    unsigned short* __restrict__ Q, unsigned short* __restrict__ K,
    unsigned short* __restrict__ V)
{
    const unsigned short* W; const float* b; unsigned short* O; int mode;
    if (blockIdx.z == 0)      { W = Wq; b = bq; O = Q; mode = 0; }
    else if (blockIdx.z == 1) { W = Wk; b = bk; O = K; mode = 0; }
    else                      { W = Wv; b = bv; O = V; mode = 1; }
    gemm_body(A, W, b, O, nullptr, mode);
}

__global__ __launch_bounds__(256) void gemm_out_k(
    const unsigned short* __restrict__ A, const unsigned short* __restrict__ W,
    const float* __restrict__ bias, float* __restrict__ O)
{
    gemm_body(A, W, bias, nullptr, O, 2);
}

// ---------------------------------------------------------------------------
// Kernel 3a: split-K flash attention (r18 = r15 base + 6 blocks/CU).
// SESSION MODEL (r3..r7 evidence): attn_split is LATENCY/TLP-bound (~31us vs
// ~10us throughput floor): occupancy 4->5 won (r13), LDS-read amortization at
// 4/CU was null (r16), 1/CU lost big (r17). Lever = waves/SIMD.
// r18: Pl stride 72->68 shorts: LDS 27648->27136 B, 163840/27136 = 6.04 ->
// 6 blocks/CU (+20% TLP). Stride 136 B keeps b64 alignment; af-read bank
// pattern improves (34-word stride: 2*l16 distinct across 16 lanes).
// r13 (kept): swapped QK^T, packed ds_write_b64, compile-time column mask,
// 2-shuffle l-reduction. r15 (kept): setprio around MFMA.
// r14 POST-MORTEM: never fuse cross-block reductions via device-scope atomics
// (L2 writeback+invalidate storm on non-coherent XCDs: attn 9->74us).
// r17 POST-MORTEM: never drop attn below ~5 blocks/CU for pipelining tricks.
// r11: grid (bh, sidx) so XCD = bh%8.
// ---------------------------------------------------------------------------
__global__ __launch_bounds__(256, 6) void attn_split(
    const unsigned short* __restrict__ Q, const unsigned short* __restrict__ K,
    const unsigned short* __restrict__ Vt, const float* __restrict__ attn_bias,
    unsigned short* __restrict__ Opart, float* __restrict__ lpart)
{
    __shared__ __align__(16) unsigned short Kl[64 * 64];
    __shared__ __align__(16) unsigned short Vl[64 * 64];       // [hd][key]
    __shared__ __align__(16) unsigned short Pl[4][16 * PSTR];  // [q(16)][key+pad]
    __shared__ float biasl[8][64];

    const int tid  = threadIdx.x;
    const int w    = tid >> 6;
    const int lane = tid & 63;
    const int quad = lane >> 4;
    const int l16  = lane & 15;
    const int lr   = lane >> 3;
    const int lc   = lane & 7;
    const int sidx = blockIdx.y;
    const int bh   = blockIdx.x;
    const int h    = bh & 7;
    const int bx   = BX_OF[sidx];
    const int sp   = SP_OF[sidx];
    const int q0   = bx * 64;
    const int kt0  = sp * 4;
    const int kt1  = min(kt0 + 4, bx + 1);
    const bool use_bias = (q0 < 512) && (sp < 2);   // block-uniform

    const int qrow  = q0 + 16 * w + l16;
    const int brow2 = 2 * w + (l16 >> 3);           // local q-node (8 rows per node)

    if (use_bias) {
        for (int i = tid; i < 512; i += 256) {
            int nq = (q0 >> 3) + (i >> 6);
            biasl[i >> 6][i & 63] = attn_bias[h * 4096 + nq * 64 + (i & 63)];
        }
    }

    const unsigned short* Qbh = Q  + (long)bh * T_SEQ * HDIM;
    const unsigned short* Kbh = K  + (long)bh * T_SEQ * HDIM;
    const unsigned short* Vbh = Vt + (long)bh * HDIM * T_SEQ;   // [hd][t]

    short8 qf[2];
    {
        qf[0] = *(const short8*)&Qbh[(long)qrow * HDIM + 8 * quad];
        qf[1] = *(const short8*)&Qbh[(long)qrow * HDIM + 32 + 8 * quad];
    }

    f32x4 oacc[4] = {};
    float lsum = 0.f;

    for (int kt = kt0; kt < kt1; ++kt) {
        const int k0 = kt * 64;
        __syncthreads();
        for (int i = 0; i < 2; ++i) {
            int r0 = 16 * w + 8 * i;
            int r  = r0 + lr;
            int c  = lc ^ (r & 7);
            gload_lds16(&Kbh[(long)(k0 + r) * HDIM + c * 8], &Kl[r0 * 64]);
            gload_lds16(&Vbh[(long)r * T_SEQ + k0 + c * 8], &Vl[r0 * 64]);
        }
        __syncthreads();

        // S^T = K Q^T (swapped): s[ct][reg] = S[key=16ct+4quad+reg][q=l16]
        f32x4 s[4] = {};
        __builtin_amdgcn_s_setprio(1);
        for (int st = 0; st < 2; ++st) {
            const int pc = ((4 * st + quad) ^ (l16 & 7)) * 8;
            for (int ct = 0; ct < 4; ++ct) {
                short8 kf = *(const short8*)&Kl[(16 * ct + l16) * 64 + pc];
                s[ct] = __builtin_amdgcn_mfma_f32_16x16x32_bf16(kf, qf[st], s[ct], 0, 0, 0);
            }
        }
        __builtin_amdgcn_s_setprio(0);

        // P = exp(S*scale + bias) with masking; keys lane-local -> ds_write_b64
        const bool diag = (kt == bx);
        #pragma unroll
        for (int ct = 0; ct < 4; ++ct) {
            const int kbase = k0 + 16 * ct + 4 * quad;
            float bval = use_bias ? biasl[brow2][(k0 >> 3) + 2 * ct + (quad >> 1)] : 0.f;
            float pv[4];
            #pragma unroll
            for (int reg = 0; reg < 4; ++reg) {
                float v = s[ct][reg] * 0.125f + bval;
                bool keep = !(quad == 3 && reg == 3);   // key%16==15 column mask
                if (diag) keep = keep && (kbase + reg <= qrow);
                float p = keep ? __expf(v) : 0.f;
                lsum += p;
                pv[reg] = p;
            }
            uint2 d;
            d.x = (unsigned)f2bf(pv[0]) | ((unsigned)f2bf(pv[1]) << 16);
            d.y = (unsigned)f2bf(pv[2]) | ((unsigned)f2bf(pv[3]) << 16);
            *(uint2*)&Pl[w][l16 * PSTR + 16 * ct + 4 * quad] = d;
        }

        // O += P V; swizzled V fragment reads (Pl layout row=q, col=key)
        __builtin_amdgcn_s_setprio(1);
        for (int st = 0; st < 2; ++st) {
            const int pc = ((4 * st + quad) ^ (l16 & 7)) * 8;
            short8 af = *(const short8*)&Pl[w][l16 * PSTR + 32 * st + 8 * quad];
            for (int ct = 0; ct < 4; ++ct) {
                short8 bf = *(const short8*)&Vl[(16 * ct + l16) * 64 + pc];
                oacc[ct] = __builtin_amdgcn_mfma_f32_16x16x32_bf16(af, bf, oacc[ct], 0, 0, 0);
            }
        }
        __builtin_amdgcn_s_setprio(0);
    }

    // row-sum lives split across the 4 quads of each q-row: reduce lanes ^16,^32
    lsum += __shfl_xor(lsum, 16);
    lsum += __shfl_xor(lsum, 32);

    // partial epilogue (unnormalized, bf16); oacc layout:
    // oacc[ct][reg] = O[q=16w+4quad+reg][hd=16ct+l16]
    const long p = (long)bh * NSPLIT_TOT + sidx;
    unsigned short* Op = Opart + p * 4096;
    for (int ct = 0; ct < 4; ++ct)
        for (int reg = 0; reg < 4; ++reg)
            Op[(16 * w + 4 * quad + reg) * 64 + 16 * ct + l16] = f2bf(oacc[ct][reg]);
    if (quad == 0)
        lpart[p * 64 + 16 * w + l16] = lsum;
}

// ---------------------------------------------------------------------------
// Kernel 3b: combine bf16 splits (plain sum), normalize, write Y bf16 (B,T,C)
// r11: grid (bh, bx) so XCD = bh%8 matches the attn_split writers.
// ---------------------------------------------------------------------------
__global__ __launch_bounds__(256) void attn_combine(
    const unsigned short* __restrict__ Opart, const float* __restrict__ lpart,
    unsigned short* __restrict__ Y)
{
    const int bx = blockIdx.y, bh = blockIdx.x;
    const int b = bh >> 3, h = bh & 7;
    const int ns = (bx >> 2) + 1;
    const long p0 = (long)bh * NSPLIT_TOT + CUM_OF[bx];
    const int tid = threadIdx.x;
    const int qr = tid >> 2;
    const int hs = (tid & 3) * 16;

    float L = 0.f;
    for (int s = 0; s < ns; ++s) L += lpart[(p0 + s) * 64 + qr];

    float acc[16] = {};
    for (int s = 0; s < ns; ++s) {
        const unsigned short* op = Opart + (p0 + s) * 4096 + qr * 64 + hs;
        short8 v0 = *(const short8*)op;
        short8 v1 = *(const short8*)(op + 8);
        for (int k = 0; k < 8; ++k) {
            acc[k]     += bf2f((unsigned short)v0[k]);
            acc[k + 8] += bf2f((unsigned short)v1[k]);
        }
    }
    float inv = 1.f / L;
    int q = bx * 64 + qr;
    unsigned short* y = Y + ((long)b * T_SEQ + q) * C_DIM + h * HDIM + hs;
    for (int j4 = 0; j4 < 4; ++j4) {
        ushort4 o;
        o.x = f2bf(acc[4 * j4 + 0] * inv); o.y = f2bf(acc[4 * j4 + 1] * inv);
        o.z = f2bf(acc[4 * j4 + 2] * inv); o.w = f2bf(acc[4 * j4 + 3] * inv);
        *(ushort4*)(y + 4 * j4) = o;
    }
}

// ---------------------------------------------------------------------------
extern "C" void kernel_launch(void* const* d_in, const int* in_sizes, int n_in,
                              void* d_out, int out_size, void* d_ws, size_t ws_size,
                              hipStream_t stream)
{
    const float* x         = (const float*)d_in[0];
    const float* attn_bias = (const float*)d_in[1];
    const float* Wq = (const float*)d_in[2]; const float* bq = (const float*)d_in[3];
    const float* Wk = (const float*)d_in[4]; const float* bk = (const float*)d_in[5];
    const float* Wv = (const float*)d_in[6]; const float* bv = (const float*)d_in[7];
    const float* Wp = (const float*)d_in[8]; const float* bp = (const float*)d_in[9];
    float* out = (float*)d_out;

    const long NX = (long)M_ROWS * C_DIM;    // 2,097,152
    const long NW = (long)C_DIM * C_DIM;     // 262,144

    unsigned short* xb  = (unsigned short*)d_ws;
    unsigned short* wqb = xb  + NX;
    unsigned short* wkb = wqb + NW;
    unsigned short* wvb = wkb + NW;
    unsigned short* wpb = wvb + NW;
    unsigned short* Qb  = wpb + NW;
    unsigned short* Kb  = Qb  + NX;
    unsigned short* Vtb = Kb  + NX;          // transposed (B,H,HD,T)
    unsigned short* Yb  = Vtb + NX;
    unsigned short* Opart = Yb + NX;         // 32*40 x 64x64 bf16 = 10.5 MB
    float* lpart = (float*)(Opart + (long)32 * NSPLIT_TOT * 4096);

    long n4 = (NX + 4 * NW) / 4;
    cast_all<<<dim3((unsigned)(n4 / 256)), 256, 0, stream>>>(
        x, Wq, Wk, Wv, Wp, xb, wqb, wkb, wvb, wpb);

    gemm_qkv<<<dim3(M_ROWS / 128, C_DIM / 64, 3), 256, 0, stream>>>(
        xb, wqb, wkb, wvb, bq, bk, bv, Qb, Kb, Vtb);

    attn_split<<<dim3(B_BATCH * H_HEADS, NSPLIT_TOT), 256, 0, stream>>>(
        Qb, Kb, Vtb, attn_bias, Opart, lpart);

    attn_combine<<<dim3(B_BATCH * H_HEADS, T_SEQ / 64), 256, 0, stream>>>(
        Opart, lpart, Yb);

    gemm_out_k<<<dim3(M_ROWS / 128, C_DIM / 64), 256, 0, stream>>>(
        Yb, wpb, bp, out);
}

// Round 9
// 121.839 us; speedup vs baseline: 1.0811x; 1.0008x over previous
//
#include <hip/hip_runtime.h>

#define T_SEQ 1024
#define C_DIM 512
#define H_HEADS 8
#define HDIM 64
#define B_BATCH 4
#define M_ROWS (B_BATCH * T_SEQ)   // 4096
#define NSPLIT_TOT 40              // sum over bx of ceil((bx+1)/4)
#define PSTR 68                    // Pl row stride (r18: 27.1KB -> 6 blocks/CU)

typedef __attribute__((ext_vector_type(8))) short short8;
typedef __attribute__((ext_vector_type(4))) float f32x4;

__device__ __forceinline__ unsigned short f2bf(float f) {
    unsigned u = __builtin_bit_cast(unsigned, f);
    u += 0x7FFFu + ((u >> 16) & 1u);   // round-to-nearest-even
    return (unsigned short)(u >> 16);
}

__device__ __forceinline__ float bf2f(unsigned short u) {
    return __builtin_bit_cast(float, (unsigned)u << 16);
}

// async global->LDS, 16B per lane; LDS dest = uniform base + lane*16
__device__ __forceinline__ void gload_lds16(const unsigned short* g, unsigned short* l) {
    __builtin_amdgcn_global_load_lds(
        (const __attribute__((address_space(1))) unsigned int*)(const void*)g,
        (__attribute__((address_space(3))) unsigned int*)(void*)l, 16, 0, 0);
}

__device__ __constant__ unsigned char BX_OF[NSPLIT_TOT] =
    {0,1,2,3,4,4,5,5,6,6,7,7,8,8,8,9,9,9,10,10,10,11,11,11,
     12,12,12,12,13,13,13,13,14,14,14,14,15,15,15,15};
__device__ __constant__ unsigned char SP_OF[NSPLIT_TOT] =
    {0,0,0,0,0,1,0,1,0,1,0,1,0,1,2,0,1,2,0,1,2,0,1,2,
     0,1,2,3,0,1,2,3,0,1,2,3,0,1,2,3};
__device__ __constant__ unsigned char CUM_OF[16] =
    {0,1,2,3,4,6,8,10,12,15,18,21,24,28,32,36};

// ---------------------------------------------------------------------------
// Kernel 1: one-shot cast of x + 4 weight matrices to bf16 (r4/r5: fusing the
// cast into GEMM staging costs ~196 MB of per-block fp32 re-reads — never).
// ---------------------------------------------------------------------------
__global__ __launch_bounds__(256) void cast_all(
    const float* __restrict__ x,
    const float* __restrict__ wq, const float* __restrict__ wk,
    const float* __restrict__ wv, const float* __restrict__ wp,
    unsigned short* __restrict__ xb,
    unsigned short* __restrict__ wqb, unsigned short* __restrict__ wkb,
    unsigned short* __restrict__ wvb, unsigned short* __restrict__ wpb)
{
    const long NX = (long)M_ROWS * C_DIM;
    const long NW = (long)C_DIM * C_DIM;
    long i4 = (long)blockIdx.x * blockDim.x + threadIdx.x;
    long base = i4 * 4;
    const float* src; unsigned short* dst; long off;
    if (base < NX) { src = x; dst = xb; off = base; }
    else {
        long r = base - NX;
        int w = (int)(r >> 18);
        off = r & (NW - 1);
        switch (w) {
            case 0:  src = wq; dst = wqb; break;
            case 1:  src = wk; dst = wkb; break;
            case 2:  src = wv; dst = wvb; break;
            default: src = wp; dst = wpb; break;
        }
    }
    float4 v = *(const float4*)(src + off);
    ushort4 o;
    o.x = f2bf(v.x); o.y = f2bf(v.y); o.z = f2bf(v.z); o.w = f2bf(v.w);
    *(ushort4*)(dst + off) = o;
}

// ---------------------------------------------------------------------------
// GEMM, BM=128 x BN=64 tile (occupancy-balanced: qkv 768 blocks = 3/CU exact,
// out 256 blocks = 1/CU exact).
// r12 (frozen): T4 counted-vmcnt pipeline, dbuf LDS 48 KB, XOR chunk swizzle.
// mode 0: bf16 (B,H,T,HD); mode 1: bf16 (B,H,HD,T) via swapped MFMA operands;
// mode 2: fp32 M x N.
// ---------------------------------------------------------------------------
__device__ __forceinline__ void gemm_body(
    const unsigned short* __restrict__ A,
    const unsigned short* __restrict__ W,
    const float* __restrict__ bias,
    unsigned short* __restrict__ Obf,
    float* __restrict__ Of,
    int mode)
{
    __shared__ __align__(16) unsigned short Atile[2][128 * 64];
    __shared__ __align__(16) unsigned short Btile[2][64 * 64];

    const int tid  = threadIdx.x;
    const int w    = tid >> 6;
    const int lane = tid & 63;
    const int quad = lane >> 4;
    const int l16  = lane & 15;
    const int m0   = blockIdx.x * 128;
    const int n0   = blockIdx.y * 64;

    f32x4 acc[2][4] = {};

    const int lr = lane >> 3;
    const int lc = lane & 7;

    auto stage = [&](int buf, int kk) {
        for (int i = 0; i < 4; ++i) {
            int r0 = 32 * w + 8 * i;
            int r  = r0 + lr;
            int c  = lc ^ (r & 7);      // XOR swizzle
            gload_lds16(&A[(long)(m0 + r) * 512 + kk + c * 8], &Atile[buf][r0 * 64]);
        }
        for (int i = 0; i < 2; ++i) {
            int r0 = 16 * w + 8 * i;
            int r  = r0 + lr;
            int c  = lc ^ (r & 7);
            gload_lds16(&W[(long)(n0 + r) * 512 + kk + c * 8], &Btile[buf][r0 * 64]);
        }
    };

    stage(0, 0);

    #pragma unroll
    for (int k0 = 0; k0 < 512; k0 += 64) {
        const int cur = (k0 >> 6) & 1;
        if (k0 + 64 < 512) {
            __builtin_amdgcn_sched_barrier(0);
            stage(cur ^ 1, k0 + 64);
            asm volatile("s_waitcnt vmcnt(6)" ::: "memory");
        } else {
            asm volatile("s_waitcnt vmcnt(0)" ::: "memory");
        }
        __builtin_amdgcn_s_barrier();
        __builtin_amdgcn_sched_barrier(0);

        for (int st = 0; st < 2; ++st) {
            const int pc = ((4 * st + quad) ^ (l16 & 7)) * 8;
            short8 af[2], bf[4];
            for (int i = 0; i < 2; ++i)
                af[i] = *(const short8*)&Atile[cur][(32 * w + 16 * i + l16) * 64 + pc];
            for (int j = 0; j < 4; ++j)
                bf[j] = *(const short8*)&Btile[cur][(16 * j + l16) * 64 + pc];
            for (int i = 0; i < 2; ++i)
                for (int j = 0; j < 4; ++j)
                    acc[i][j] = (mode == 1)
                        ? __builtin_amdgcn_mfma_f32_16x16x32_bf16(bf[j], af[i], acc[i][j], 0, 0, 0)
                        : __builtin_amdgcn_mfma_f32_16x16x32_bf16(af[i], bf[j], acc[i][j], 0, 0, 0);
        }

        __builtin_amdgcn_sched_barrier(0);
        __builtin_amdgcn_s_barrier();
    }

    if (mode == 1) {
        for (int j = 0; j < 4; ++j) {
            for (int reg = 0; reg < 4; ++reg) {
                int n = n0 + 16 * j + 4 * quad + reg;
                int h = n >> 6, hd = n & 63;
                float bv = bias[n];
                for (int i = 0; i < 2; ++i) {
                    int t = m0 + 32 * w + 16 * i + l16;
                    int b = t >> 10, tl = t & 1023;
                    Obf[(((long)(b * H_HEADS + h)) * HDIM + hd) * T_SEQ + tl] =
                        f2bf(acc[i][j][reg] + bv);
                }
            }
        }
    } else {
        for (int j = 0; j < 4; ++j) {
            int col = n0 + 16 * j + l16;
            float bv = bias[col];
            for (int i = 0; i < 2; ++i) {
                for (int reg = 0; reg < 4; ++reg) {
                    int row = m0 + 32 * w + 16 * i + 4 * quad + reg;
                    float v = acc[i][j][reg] + bv;
                    if (mode == 2) {
                        Of[(long)row * 512 + col] = v;
                    } else {
                        int b = row >> 10, t = row & 1023;
                        int h = col >> 6,  hd = col & 63;
                        Obf[(((long)(b * H_HEADS + h)) * T_SEQ + t) * HDIM + hd] = f2bf(v);
                    }
                }
            }
        }
    }
}

__global__ __launch_bounds__(256) void gemm_qkv(
    const unsigned short* __restrict__ A,
    const unsigned short* __restrict__ Wq, const unsigned short* __restrict__ Wk,
    const unsigned short* __restrict__ Wv,
    const float* __restrict__ bq, const float* __restrict__ bk, const float* __restrict__ bv,
    unsigned short* __restrict__ Q, unsigned short* __restrict__ K,
    unsigned short* __restrict__ V)
{
    const unsigned short* W; const float* b; unsigned short* O; int mode;
    if (blockIdx.z == 0)      { W = Wq; b = bq; O = Q; mode = 0; }
    else if (blockIdx.z == 1) { W = Wk; b = bk; O = K; mode = 0; }
    else                      { W = Wv; b = bv; O = V; mode = 1; }
    gemm_body(A, W, b, O, nullptr, mode);
}

__global__ __launch_bounds__(256) void gemm_out_k(
    const unsigned short* __restrict__ A, const unsigned short* __restrict__ W,
    const float* __restrict__ bias, float* __restrict__ O)
{
    gemm_body(A, W, bias, nullptr, O, 2);
}

// ---------------------------------------------------------------------------
// Kernel 3a: split-K flash attention (r19 = r18 + split-stage pipeline).
// SESSION MODEL: attn ~29us vs ~8-10us floor (r4 arithmetic); TLP-saturated
// (r8 null at 6/CU), not LDS-throughput-bound (r16 null). Remaining candidate:
// per-tile staging drain with ZERO compute cover (stage -> immediate vmcnt(0)
// via __syncthreads). r19 exploits Kl-only-read-in-QKT / Vl-only-read-in-PV:
//   [bar: Vl free + K(t) ready] issueV(t); QKT(t)
//   [bar: Kl free]              issueK(t+1); softmax; vmcnt(2) (V self-wait)
//   [bar: V ready]              PV(t); vmcnt(0) (K(t+1) self-wait, covered)
// V loads fly under QKT+softmax, K loads under softmax+PV. Self-wait BEFORE
// the rendezvous barrier guarantees all-waves-resident (the race class that
// killed naive versions). 3 barriers/tile (+1) vs ~400cyc recovered stall.
// LDS/occupancy/VGPR unchanged: 27136 B, 6 blocks/CU.
// r13/r15/r18 kept. r14: no cross-block atomics. r17: never <5 blocks/CU.
// r11: grid (bh, sidx) so XCD = bh%8.
// ---------------------------------------------------------------------------
__global__ __launch_bounds__(256, 6) void attn_split(
    const unsigned short* __restrict__ Q, const unsigned short* __restrict__ K,
    const unsigned short* __restrict__ Vt, const float* __restrict__ attn_bias,
    unsigned short* __restrict__ Opart, float* __restrict__ lpart)
{
    __shared__ __align__(16) unsigned short Kl[64 * 64];
    __shared__ __align__(16) unsigned short Vl[64 * 64];       // [hd][key]
    __shared__ __align__(16) unsigned short Pl[4][16 * PSTR];  // [q(16)][key+pad]
    __shared__ float biasl[8][64];

    const int tid  = threadIdx.x;
    const int w    = tid >> 6;
    const int lane = tid & 63;
    const int quad = lane >> 4;
    const int l16  = lane & 15;
    const int lr   = lane >> 3;
    const int lc   = lane & 7;
    const int sidx = blockIdx.y;
    const int bh   = blockIdx.x;
    const int h    = bh & 7;
    const int bx   = BX_OF[sidx];
    const int sp   = SP_OF[sidx];
    const int q0   = bx * 64;
    const int kt0  = sp * 4;
    const int kt1  = min(kt0 + 4, bx + 1);
    const bool use_bias = (q0 < 512) && (sp < 2);   // block-uniform

    const int qrow  = q0 + 16 * w + l16;
    const int brow2 = 2 * w + (l16 >> 3);           // local q-node (8 rows per node)

    if (use_bias) {
        for (int i = tid; i < 512; i += 256) {
            int nq = (q0 >> 3) + (i >> 6);
            biasl[i >> 6][i & 63] = attn_bias[h * 4096 + nq * 64 + (i & 63)];
        }
    }

    const unsigned short* Qbh = Q  + (long)bh * T_SEQ * HDIM;
    const unsigned short* Kbh = K  + (long)bh * T_SEQ * HDIM;
    const unsigned short* Vbh = Vt + (long)bh * HDIM * T_SEQ;   // [hd][t]

    short8 qf[2];
    {
        qf[0] = *(const short8*)&Qbh[(long)qrow * HDIM + 8 * quad];
        qf[1] = *(const short8*)&Qbh[(long)qrow * HDIM + 32 + 8 * quad];
    }

    // split staging: 2 gload_lds each (K rows / V rows), vmcnt-countable
    auto issueK = [&](int k0) {
        for (int i = 0; i < 2; ++i) {
            int r0 = 16 * w + 8 * i;
            int r  = r0 + lr;
            int c  = lc ^ (r & 7);
            gload_lds16(&Kbh[(long)(k0 + r) * HDIM + c * 8], &Kl[r0 * 64]);
        }
    };
    auto issueV = [&](int k0) {
        for (int i = 0; i < 2; ++i) {
            int r0 = 16 * w + 8 * i;
            int r  = r0 + lr;
            int c  = lc ^ (r & 7);
            gload_lds16(&Vbh[(long)r * T_SEQ + k0 + c * 8], &Vl[r0 * 64]);
        }
    };

    f32x4 oacc[4] = {};
    float lsum = 0.f;

    // prologue: drain bias/Q traffic so loop vmcnt counts are exact, then
    // issue K(kt0) and self-wait (no cover available before the first tile).
    asm volatile("s_waitcnt vmcnt(0) lgkmcnt(0)" ::: "memory");
    __builtin_amdgcn_sched_barrier(0);
    issueK(kt0 * 64);
    asm volatile("s_waitcnt vmcnt(0)" ::: "memory");
    __builtin_amdgcn_sched_barrier(0);

    for (int kt = kt0; kt < kt1; ++kt) {
        const int k0 = kt * 64;
        const bool more = (kt + 1 < kt1);

        __builtin_amdgcn_s_barrier();        // Vl free + K(kt) all-ready (+biasl)
        __builtin_amdgcn_sched_barrier(0);
        issueV(k0);                          // flies under QKT + softmax
        __builtin_amdgcn_sched_barrier(0);

        // S^T = K Q^T (swapped): s[ct][reg] = S[key=16ct+4quad+reg][q=l16]
        f32x4 s[4] = {};
        __builtin_amdgcn_s_setprio(1);
        for (int st = 0; st < 2; ++st) {
            const int pc = ((4 * st + quad) ^ (l16 & 7)) * 8;
            for (int ct = 0; ct < 4; ++ct) {
                short8 kf = *(const short8*)&Kl[(16 * ct + l16) * 64 + pc];
                s[ct] = __builtin_amdgcn_mfma_f32_16x16x32_bf16(kf, qf[st], s[ct], 0, 0, 0);
            }
        }
        __builtin_amdgcn_s_setprio(0);

        __builtin_amdgcn_sched_barrier(0);
        __builtin_amdgcn_s_barrier();        // Kl free (all waves done QKT reads)
        __builtin_amdgcn_sched_barrier(0);
        if (more) issueK(k0 + 64);           // flies under softmax + PV
        __builtin_amdgcn_sched_barrier(0);

        // P = exp(S*scale + bias) with masking; keys lane-local -> ds_write_b64
        const bool diag = (kt == bx);
        #pragma unroll
        for (int ct = 0; ct < 4; ++ct) {
            const int kbase = k0 + 16 * ct + 4 * quad;
            float bval = use_bias ? biasl[brow2][(k0 >> 3) + 2 * ct + (quad >> 1)] : 0.f;
            float pv[4];
            #pragma unroll
            for (int reg = 0; reg < 4; ++reg) {
                float v = s[ct][reg] * 0.125f + bval;
                bool keep = !(quad == 3 && reg == 3);   // key%16==15 column mask
                if (diag) keep = keep && (kbase + reg <= qrow);
                float p = keep ? __expf(v) : 0.f;
                lsum += p;
                pv[reg] = p;
            }
            uint2 d;
            d.x = (unsigned)f2bf(pv[0]) | ((unsigned)f2bf(pv[1]) << 16);
            d.y = (unsigned)f2bf(pv[2]) | ((unsigned)f2bf(pv[3]) << 16);
            *(uint2*)&Pl[w][l16 * PSTR + 16 * ct + 4 * quad] = d;
        }

        // V self-wait: outstanding = V(kt)[2] (+K(kt+1)[2] if issued)
        if (more) asm volatile("s_waitcnt vmcnt(2)" ::: "memory");
        else      asm volatile("s_waitcnt vmcnt(0)" ::: "memory");
        __builtin_amdgcn_sched_barrier(0);
        __builtin_amdgcn_s_barrier();        // V all-ready across waves
        __builtin_amdgcn_sched_barrier(0);

        // O += P V; swizzled V fragment reads (Pl layout row=q, col=key)
        __builtin_amdgcn_s_setprio(1);
        for (int st = 0; st < 2; ++st) {
            const int pc = ((4 * st + quad) ^ (l16 & 7)) * 8;
            short8 af = *(const short8*)&Pl[w][l16 * PSTR + 32 * st + 8 * quad];
            for (int ct = 0; ct < 4; ++ct) {
                short8 bf = *(const short8*)&Vl[(16 * ct + l16) * 64 + pc];
                oacc[ct] = __builtin_amdgcn_mfma_f32_16x16x32_bf16(af, bf, oacc[ct], 0, 0, 0);
            }
        }
        __builtin_amdgcn_s_setprio(0);
        __builtin_amdgcn_sched_barrier(0);

        // K(kt+1) self-wait (covered by softmax+PV), before loop-top barrier
        if (more) {
            asm volatile("s_waitcnt vmcnt(0)" ::: "memory");
            __builtin_amdgcn_sched_barrier(0);
        }
    }

    // row-sum lives split across the 4 quads of each q-row: reduce lanes ^16,^32
    lsum += __shfl_xor(lsum, 16);
    lsum += __shfl_xor(lsum, 32);

    // partial epilogue (unnormalized, bf16); oacc layout:
    // oacc[ct][reg] = O[q=16w+4quad+reg][hd=16ct+l16]
    const long p = (long)bh * NSPLIT_TOT + sidx;
    unsigned short* Op = Opart + p * 4096;
    for (int ct = 0; ct < 4; ++ct)
        for (int reg = 0; reg < 4; ++reg)
            Op[(16 * w + 4 * quad + reg) * 64 + 16 * ct + l16] = f2bf(oacc[ct][reg]);
    if (quad == 0)
        lpart[p * 64 + 16 * w + l16] = lsum;
}

// ---------------------------------------------------------------------------
// Kernel 3b: combine bf16 splits (plain sum), normalize, write Y bf16 (B,T,C)
// r11: grid (bh, bx) so XCD = bh%8 matches the attn_split writers.
// ---------------------------------------------------------------------------
__global__ __launch_bounds__(256) void attn_combine(
    const unsigned short* __restrict__ Opart, const float* __restrict__ lpart,
    unsigned short* __restrict__ Y)
{
    const int bx = blockIdx.y, bh = blockIdx.x;
    const int b = bh >> 3, h = bh & 7;
    const int ns = (bx >> 2) + 1;
    const long p0 = (long)bh * NSPLIT_TOT + CUM_OF[bx];
    const int tid = threadIdx.x;
    const int qr = tid >> 2;
    const int hs = (tid & 3) * 16;

    float L = 0.f;
    for (int s = 0; s < ns; ++s) L += lpart[(p0 + s) * 64 + qr];

    float acc[16] = {};
    for (int s = 0; s < ns; ++s) {
        const unsigned short* op = Opart + (p0 + s) * 4096 + qr * 64 + hs;
        short8 v0 = *(const short8*)op;
        short8 v1 = *(const short8*)(op + 8);
        for (int k = 0; k < 8; ++k) {
            acc[k]     += bf2f((unsigned short)v0[k]);
            acc[k + 8] += bf2f((unsigned short)v1[k]);
        }
    }
    float inv = 1.f / L;
    int q = bx * 64 + qr;
    unsigned short* y = Y + ((long)b * T_SEQ + q) * C_DIM + h * HDIM + hs;
    for (int j4 = 0; j4 < 4; ++j4) {
        ushort4 o;
        o.x = f2bf(acc[4 * j4 + 0] * inv); o.y = f2bf(acc[4 * j4 + 1] * inv);
        o.z = f2bf(acc[4 * j4 + 2] * inv); o.w = f2bf(acc[4 * j4 + 3] * inv);
        *(ushort4*)(y + 4 * j4) = o;
    }
}

// ---------------------------------------------------------------------------
extern "C" void kernel_launch(void* const* d_in, const int* in_sizes, int n_in,
                              void* d_out, int out_size, void* d_ws, size_t ws_size,
                              hipStream_t stream)
{
    const float* x         = (const float*)d_in[0];
    const float* attn_bias = (const float*)d_in[1];
    const float* Wq = (const float*)d_in[2]; const float* bq = (const float*)d_in[3];
    const float* Wk = (const float*)d_in[4]; const float* bk = (const float*)d_in[5];
    const float* Wv = (const float*)d_in[6]; const float* bv = (const float*)d_in[7];
    const float* Wp = (const float*)d_in[8]; const float* bp = (const float*)d_in[9];
    float* out = (float*)d_out;

    const long NX = (long)M_ROWS * C_DIM;    // 2,097,152
    const long NW = (long)C_DIM * C_DIM;     // 262,144

    unsigned short* xb  = (unsigned short*)d_ws;
    unsigned short* wqb = xb  + NX;
    unsigned short* wkb = wqb + NW;
    unsigned short* wvb = wkb + NW;
    unsigned short* wpb = wvb + NW;
    unsigned short* Qb  = wpb + NW;
    unsigned short* Kb  = Qb  + NX;
    unsigned short* Vtb = Kb  + NX;          // transposed (B,H,HD,T)
    unsigned short* Yb  = Vtb + NX;
    unsigned short* Opart = Yb + NX;         // 32*40 x 64x64 bf16 = 10.5 MB
    float* lpart = (float*)(Opart + (long)32 * NSPLIT_TOT * 4096);

    long n4 = (NX + 4 * NW) / 4;
    cast_all<<<dim3((unsigned)(n4 / 256)), 256, 0, stream>>>(
        x, Wq, Wk, Wv, Wp, xb, wqb, wkb, wvb, wpb);

    gemm_qkv<<<dim3(M_ROWS / 128, C_DIM / 64, 3), 256, 0, stream>>>(
        xb, wqb, wkb, wvb, bq, bk, bv, Qb, Kb, Vtb);

    attn_split<<<dim3(B_BATCH * H_HEADS, NSPLIT_TOT), 256, 0, stream>>>(
        Qb, Kb, Vtb, attn_bias, Opart, lpart);

    attn_combine<<<dim3(B_BATCH * H_HEADS, T_SEQ / 64), 256, 0, stream>>>(
        Opart, lpart, Yb);

    gemm_out_k<<<dim3(M_ROWS / 128, C_DIM / 64), 256, 0, stream>>>(
        Yb, wpb, bp, out);
}

// Round 10
// 120.756 us; speedup vs baseline: 1.0908x; 1.0090x over previous
//
#include <hip/hip_runtime.h>

#define T_SEQ 1024
#define C_DIM 512
#define H_HEADS 8
#define HDIM 64
#define B_BATCH 4
#define M_ROWS (B_BATCH * T_SEQ)   // 4096
#define NSPLIT_TOT 40              // sum over bx of ceil((bx+1)/4)

typedef __attribute__((ext_vector_type(8))) short short8;
typedef __attribute__((ext_vector_type(4))) float f32x4;

__device__ __forceinline__ unsigned short f2bf(float f) {
    unsigned u = __builtin_bit_cast(unsigned, f);
    u += 0x7FFFu + ((u >> 16) & 1u);   // round-to-nearest-even
    return (unsigned short)(u >> 16);
}

__device__ __forceinline__ float bf2f(unsigned short u) {
    return __builtin_bit_cast(float, (unsigned)u << 16);
}

// async global->LDS, 16B per lane; LDS dest = uniform base + lane*16
__device__ __forceinline__ void gload_lds16(const unsigned short* g, unsigned short* l) {
    __builtin_amdgcn_global_load_lds(
        (const __attribute__((address_space(1))) unsigned int*)(const void*)g,
        (__attribute__((address_space(3))) unsigned int*)(void*)l, 16, 0, 0);
}

__device__ __constant__ unsigned char BX_OF[NSPLIT_TOT] =
    {0,1,2,3,4,4,5,5,6,6,7,7,8,8,8,9,9,9,10,10,10,11,11,11,
     12,12,12,12,13,13,13,13,14,14,14,14,15,15,15,15};
__device__ __constant__ unsigned char SP_OF[NSPLIT_TOT] =
    {0,0,0,0,0,1,0,1,0,1,0,1,0,1,2,0,1,2,0,1,2,0,1,2,
     0,1,2,3,0,1,2,3,0,1,2,3,0,1,2,3};
__device__ __constant__ unsigned char CUM_OF[16] =
    {0,1,2,3,4,6,8,10,12,15,18,21,24,28,32,36};

// ---------------------------------------------------------------------------
// Kernel 1: one-shot cast of x + 4 weight matrices to bf16 (r4/r5: fusing the
// cast into GEMM staging costs ~196 MB of per-block fp32 re-reads — never).
// ---------------------------------------------------------------------------
__global__ __launch_bounds__(256) void cast_all(
    const float* __restrict__ x,
    const float* __restrict__ wq, const float* __restrict__ wk,
    const float* __restrict__ wv, const float* __restrict__ wp,
    unsigned short* __restrict__ xb,
    unsigned short* __restrict__ wqb, unsigned short* __restrict__ wkb,
    unsigned short* __restrict__ wvb, unsigned short* __restrict__ wpb)
{
    const long NX = (long)M_ROWS * C_DIM;
    const long NW = (long)C_DIM * C_DIM;
    long i4 = (long)blockIdx.x * blockDim.x + threadIdx.x;
    long base = i4 * 4;
    const float* src; unsigned short* dst; long off;
    if (base < NX) { src = x; dst = xb; off = base; }
    else {
        long r = base - NX;
        int w = (int)(r >> 18);
        off = r & (NW - 1);
        switch (w) {
            case 0:  src = wq; dst = wqb; break;
            case 1:  src = wk; dst = wkb; break;
            case 2:  src = wv; dst = wvb; break;
            default: src = wp; dst = wpb; break;
        }
    }
    float4 v = *(const float4*)(src + off);
    ushort4 o;
    o.x = f2bf(v.x); o.y = f2bf(v.y); o.z = f2bf(v.z); o.w = f2bf(v.w);
    *(ushort4*)(dst + off) = o;
}

// ---------------------------------------------------------------------------
// GEMM, BM=128 x BN=64 tile (occupancy-balanced: qkv 768 blocks = 3/CU exact,
// out 256 blocks = 1/CU exact).
// r12 (frozen): T4 counted-vmcnt pipeline, dbuf LDS 48 KB, XOR chunk swizzle.
// mode 0: bf16 (B,H,T,HD); mode 1: bf16 (B,H,HD,T) via swapped MFMA operands;
// mode 2: fp32 M x N.
// ---------------------------------------------------------------------------
__device__ __forceinline__ void gemm_body(
    const unsigned short* __restrict__ A,
    const unsigned short* __restrict__ W,
    const float* __restrict__ bias,
    unsigned short* __restrict__ Obf,
    float* __restrict__ Of,
    int mode)
{
    __shared__ __align__(16) unsigned short Atile[2][128 * 64];
    __shared__ __align__(16) unsigned short Btile[2][64 * 64];

    const int tid  = threadIdx.x;
    const int w    = tid >> 6;
    const int lane = tid & 63;
    const int quad = lane >> 4;
    const int l16  = lane & 15;
    const int m0   = blockIdx.x * 128;
    const int n0   = blockIdx.y * 64;

    f32x4 acc[2][4] = {};

    const int lr = lane >> 3;
    const int lc = lane & 7;

    auto stage = [&](int buf, int kk) {
        for (int i = 0; i < 4; ++i) {
            int r0 = 32 * w + 8 * i;
            int r  = r0 + lr;
            int c  = lc ^ (r & 7);      // XOR swizzle
            gload_lds16(&A[(long)(m0 + r) * 512 + kk + c * 8], &Atile[buf][r0 * 64]);
        }
        for (int i = 0; i < 2; ++i) {
            int r0 = 16 * w + 8 * i;
            int r  = r0 + lr;
            int c  = lc ^ (r & 7);
            gload_lds16(&W[(long)(n0 + r) * 512 + kk + c * 8], &Btile[buf][r0 * 64]);
        }
    };

    stage(0, 0);

    #pragma unroll
    for (int k0 = 0; k0 < 512; k0 += 64) {
        const int cur = (k0 >> 6) & 1;
        if (k0 + 64 < 512) {
            __builtin_amdgcn_sched_barrier(0);
            stage(cur ^ 1, k0 + 64);
            asm volatile("s_waitcnt vmcnt(6)" ::: "memory");
        } else {
            asm volatile("s_waitcnt vmcnt(0)" ::: "memory");
        }
        __builtin_amdgcn_s_barrier();
        __builtin_amdgcn_sched_barrier(0);

        for (int st = 0; st < 2; ++st) {
            const int pc = ((4 * st + quad) ^ (l16 & 7)) * 8;
            short8 af[2], bf[4];
            for (int i = 0; i < 2; ++i)
                af[i] = *(const short8*)&Atile[cur][(32 * w + 16 * i + l16) * 64 + pc];
            for (int j = 0; j < 4; ++j)
                bf[j] = *(const short8*)&Btile[cur][(16 * j + l16) * 64 + pc];
            for (int i = 0; i < 2; ++i)
                for (int j = 0; j < 4; ++j)
                    acc[i][j] = (mode == 1)
                        ? __builtin_amdgcn_mfma_f32_16x16x32_bf16(bf[j], af[i], acc[i][j], 0, 0, 0)
                        : __builtin_amdgcn_mfma_f32_16x16x32_bf16(af[i], bf[j], acc[i][j], 0, 0, 0);
        }

        __builtin_amdgcn_sched_barrier(0);
        __builtin_amdgcn_s_barrier();
    }

    if (mode == 1) {
        for (int j = 0; j < 4; ++j) {
            for (int reg = 0; reg < 4; ++reg) {
                int n = n0 + 16 * j + 4 * quad + reg;
                int h = n >> 6, hd = n & 63;
                float bv = bias[n];
                for (int i = 0; i < 2; ++i) {
                    int t = m0 + 32 * w + 16 * i + l16;
                    int b = t >> 10, tl = t & 1023;
                    Obf[(((long)(b * H_HEADS + h)) * HDIM + hd) * T_SEQ + tl] =
                        f2bf(acc[i][j][reg] + bv);
                }
            }
        }
    } else {
        for (int j = 0; j < 4; ++j) {
            int col = n0 + 16 * j + l16;
            float bv = bias[col];
            for (int i = 0; i < 2; ++i) {
                for (int reg = 0; reg < 4; ++reg) {
                    int row = m0 + 32 * w + 16 * i + 4 * quad + reg;
                    float v = acc[i][j][reg] + bv;
                    if (mode == 2) {
                        Of[(long)row * 512 + col] = v;
                    } else {
                        int b = row >> 10, t = row & 1023;
                        int h = col >> 6,  hd = col & 63;
                        Obf[(((long)(b * H_HEADS + h)) * T_SEQ + t) * HDIM + hd] = f2bf(v);
                    }
                }
            }
        }
    }
}

__global__ __launch_bounds__(256) void gemm_qkv(
    const unsigned short* __restrict__ A,
    const unsigned short* __restrict__ Wq, const unsigned short* __restrict__ Wk,
    const unsigned short* __restrict__ Wv,
    const float* __restrict__ bq, const float* __restrict__ bk, const float* __restrict__ bv,
    unsigned short* __restrict__ Q, unsigned short* __restrict__ K,
    unsigned short* __restrict__ V)
{
    const unsigned short* W; const float* b; unsigned short* O; int mode;
    if (blockIdx.z == 0)      { W = Wq; b = bq; O = Q; mode = 0; }
    else if (blockIdx.z == 1) { W = Wk; b = bk; O = K; mode = 0; }
    else                      { W = Wv; b = bv; O = V; mode = 1; }
    gemm_body(A, W, b, O, nullptr, mode);
}

__global__ __launch_bounds__(256) void gemm_out_k(
    const unsigned short* __restrict__ A, const unsigned short* __restrict__ W,
    const float* __restrict__ bias, float* __restrict__ O)
{
    gemm_body(A, W, bias, nullptr, O, 2);
}

// ---------------------------------------------------------------------------
// Kernel 3a: split-K flash attention (r20 = exact r13/r3 structure, which
// remains the session-best measured config, + ns=1 direct-write fast path).
// SESSION LEDGER: r13 (swapped QK^T + packed P-writes + 5/CU) WON -6.2.
// Nulls: gemm dbuf (r11), counted vmcnt (r12), 128-row amortization (r16),
// 6/CU (r18), split-stage pipeline (r19). Losses: AGENT-atomic combine
// (r14, L2-flush storm, +43), 1/CU pairing (r17, +8.4). setprio: the only
// within-session A/B (r3 121.26 -> r5 122.05) says it COSTS ~0.8 -> removed.
// r20: splits with sidx<4 (bx 0..3, ns=1) hold the complete causal row ->
// normalize in-register (r7's verified epilogue) and write Yb directly,
// skipping Opart/lpart for 25% of rows; combine grid shrinks 16->12.
// r11: grid (bh, sidx) so XCD = bh%8.
// ---------------------------------------------------------------------------
__global__ __launch_bounds__(256, 5) void attn_split(
    const unsigned short* __restrict__ Q, const unsigned short* __restrict__ K,
    const unsigned short* __restrict__ Vt, const float* __restrict__ attn_bias,
    unsigned short* __restrict__ Opart, float* __restrict__ lpart,
    unsigned short* __restrict__ Y)
{
    __shared__ __align__(16) unsigned short Kl[64 * 64];
    __shared__ __align__(16) unsigned short Vl[64 * 64];     // [hd][key]
    __shared__ __align__(16) unsigned short Pl[4][16 * 72];  // [q(16)][key+pad]
    __shared__ float biasl[8][64];

    const int tid  = threadIdx.x;
    const int w    = tid >> 6;
    const int lane = tid & 63;
    const int quad = lane >> 4;
    const int l16  = lane & 15;
    const int lr   = lane >> 3;
    const int lc   = lane & 7;
    const int sidx = blockIdx.y;
    const int bh   = blockIdx.x;
    const int h    = bh & 7;
    const int bx   = BX_OF[sidx];
    const int sp   = SP_OF[sidx];
    const int q0   = bx * 64;
    const int kt0  = sp * 4;
    const int kt1  = min(kt0 + 4, bx + 1);
    const bool use_bias = (q0 < 512) && (sp < 2);   // block-uniform

    const int qrow  = q0 + 16 * w + l16;
    const int brow2 = 2 * w + (l16 >> 3);           // local q-node (8 rows per node)

    if (use_bias) {
        for (int i = tid; i < 512; i += 256) {
            int nq = (q0 >> 3) + (i >> 6);
            biasl[i >> 6][i & 63] = attn_bias[h * 4096 + nq * 64 + (i & 63)];
        }
    }

    const unsigned short* Qbh = Q  + (long)bh * T_SEQ * HDIM;
    const unsigned short* Kbh = K  + (long)bh * T_SEQ * HDIM;
    const unsigned short* Vbh = Vt + (long)bh * HDIM * T_SEQ;   // [hd][t]

    short8 qf[2];
    {
        qf[0] = *(const short8*)&Qbh[(long)qrow * HDIM + 8 * quad];
        qf[1] = *(const short8*)&Qbh[(long)qrow * HDIM + 32 + 8 * quad];
    }

    f32x4 oacc[4] = {};
    float lsum = 0.f;

    for (int kt = kt0; kt < kt1; ++kt) {
        const int k0 = kt * 64;
        __syncthreads();
        for (int i = 0; i < 2; ++i) {
            int r0 = 16 * w + 8 * i;
            int r  = r0 + lr;
            int c  = lc ^ (r & 7);
            gload_lds16(&Kbh[(long)(k0 + r) * HDIM + c * 8], &Kl[r0 * 64]);
            gload_lds16(&Vbh[(long)r * T_SEQ + k0 + c * 8], &Vl[r0 * 64]);
        }
        __syncthreads();

        // S^T = K Q^T (swapped): s[ct][reg] = S[key=16ct+4quad+reg][q=l16]
        f32x4 s[4] = {};
        for (int st = 0; st < 2; ++st) {
            const int pc = ((4 * st + quad) ^ (l16 & 7)) * 8;
            for (int ct = 0; ct < 4; ++ct) {
                short8 kf = *(const short8*)&Kl[(16 * ct + l16) * 64 + pc];
                s[ct] = __builtin_amdgcn_mfma_f32_16x16x32_bf16(kf, qf[st], s[ct], 0, 0, 0);
            }
        }

        // P = exp(S*scale + bias) with masking; keys lane-local -> ds_write_b64
        const bool diag = (kt == bx);
        #pragma unroll
        for (int ct = 0; ct < 4; ++ct) {
            const int kbase = k0 + 16 * ct + 4 * quad;
            float bval = use_bias ? biasl[brow2][(k0 >> 3) + 2 * ct + (quad >> 1)] : 0.f;
            float pv[4];
            #pragma unroll
            for (int reg = 0; reg < 4; ++reg) {
                float v = s[ct][reg] * 0.125f + bval;
                bool keep = !(quad == 3 && reg == 3);   // key%16==15 column mask
                if (diag) keep = keep && (kbase + reg <= qrow);
                float p = keep ? __expf(v) : 0.f;
                lsum += p;
                pv[reg] = p;
            }
            uint2 d;
            d.x = (unsigned)f2bf(pv[0]) | ((unsigned)f2bf(pv[1]) << 16);
            d.y = (unsigned)f2bf(pv[2]) | ((unsigned)f2bf(pv[3]) << 16);
            *(uint2*)&Pl[w][l16 * 72 + 16 * ct + 4 * quad] = d;
        }

        // O += P V; swizzled V fragment reads (Pl layout row=q, col=key)
        for (int st = 0; st < 2; ++st) {
            const int pc = ((4 * st + quad) ^ (l16 & 7)) * 8;
            short8 af = *(const short8*)&Pl[w][l16 * 72 + 32 * st + 8 * quad];
            for (int ct = 0; ct < 4; ++ct) {
                short8 bf = *(const short8*)&Vl[(16 * ct + l16) * 64 + pc];
                oacc[ct] = __builtin_amdgcn_mfma_f32_16x16x32_bf16(af, bf, oacc[ct], 0, 0, 0);
            }
        }
    }

    // row-sum lives split across the 4 quads of each q-row: reduce lanes ^16,^32
    lsum += __shfl_xor(lsum, 16);
    lsum += __shfl_xor(lsum, 32);          // all lanes: L of q-row l16

    if (sidx < 4) {
        // ns==1 (bx 0..3): this block holds the COMPLETE row -> normalize
        // in-register (r7-verified pattern) and write Y directly.
        const int b = bh >> 3;
        float linv[4];
        #pragma unroll
        for (int reg = 0; reg < 4; ++reg)
            linv[reg] = 1.f / __shfl(lsum, 4 * quad + reg);
        #pragma unroll
        for (int ct = 0; ct < 4; ++ct)
            #pragma unroll
            for (int reg = 0; reg < 4; ++reg) {
                int q = q0 + 16 * w + 4 * quad + reg;
                Y[((long)b * T_SEQ + q) * C_DIM + h * HDIM + 16 * ct + l16] =
                    f2bf(oacc[ct][reg] * linv[reg]);
            }
        return;
    }

    // partial epilogue (unnormalized, bf16); oacc layout:
    // oacc[ct][reg] = O[q=16w+4quad+reg][hd=16ct+l16]
    const long p = (long)bh * NSPLIT_TOT + sidx;
    unsigned short* Op = Opart + p * 4096;
    for (int ct = 0; ct < 4; ++ct)
        for (int reg = 0; reg < 4; ++reg)
            Op[(16 * w + 4 * quad + reg) * 64 + 16 * ct + l16] = f2bf(oacc[ct][reg]);
    if (quad == 0)
        lpart[p * 64 + 16 * w + l16] = lsum;
}

// ---------------------------------------------------------------------------
// Kernel 3b: combine bf16 splits (plain sum), normalize, write Y bf16 (B,T,C)
// r20: covers bx 4..15 only (bx 0..3 written directly by attn_split).
// r11: grid (bh, bx) so XCD = bh%8 matches the attn_split writers.
// ---------------------------------------------------------------------------
__global__ __launch_bounds__(256) void attn_combine(
    const unsigned short* __restrict__ Opart, const float* __restrict__ lpart,
    unsigned short* __restrict__ Y)
{
    const int bx = blockIdx.y + 4, bh = blockIdx.x;
    const int b = bh >> 3, h = bh & 7;
    const int ns = (bx >> 2) + 1;
    const long p0 = (long)bh * NSPLIT_TOT + CUM_OF[bx];
    const int tid = threadIdx.x;
    const int qr = tid >> 2;
    const int hs = (tid & 3) * 16;

    float L = 0.f;
    for (int s = 0; s < ns; ++s) L += lpart[(p0 + s) * 64 + qr];

    float acc[16] = {};
    for (int s = 0; s < ns; ++s) {
        const unsigned short* op = Opart + (p0 + s) * 4096 + qr * 64 + hs;
        short8 v0 = *(const short8*)op;
        short8 v1 = *(const short8*)(op + 8);
        for (int k = 0; k < 8; ++k) {
            acc[k]     += bf2f((unsigned short)v0[k]);
            acc[k + 8] += bf2f((unsigned short)v1[k]);
        }
    }
    float inv = 1.f / L;
    int q = bx * 64 + qr;
    unsigned short* y = Y + ((long)b * T_SEQ + q) * C_DIM + h * HDIM + hs;
    for (int j4 = 0; j4 < 4; ++j4) {
        ushort4 o;
        o.x = f2bf(acc[4 * j4 + 0] * inv); o.y = f2bf(acc[4 * j4 + 1] * inv);
        o.z = f2bf(acc[4 * j4 + 2] * inv); o.w = f2bf(acc[4 * j4 + 3] * inv);
        *(ushort4*)(y + 4 * j4) = o;
    }
}

// ---------------------------------------------------------------------------
extern "C" void kernel_launch(void* const* d_in, const int* in_sizes, int n_in,
                              void* d_out, int out_size, void* d_ws, size_t ws_size,
                              hipStream_t stream)
{
    const float* x         = (const float*)d_in[0];
    const float* attn_bias = (const float*)d_in[1];
    const float* Wq = (const float*)d_in[2]; const float* bq = (const float*)d_in[3];
    const float* Wk = (const float*)d_in[4]; const float* bk = (const float*)d_in[5];
    const float* Wv = (const float*)d_in[6]; const float* bv = (const float*)d_in[7];
    const float* Wp = (const float*)d_in[8]; const float* bp = (const float*)d_in[9];
    float* out = (float*)d_out;

    const long NX = (long)M_ROWS * C_DIM;    // 2,097,152
    const long NW = (long)C_DIM * C_DIM;     // 262,144

    unsigned short* xb  = (unsigned short*)d_ws;
    unsigned short* wqb = xb  + NX;
    unsigned short* wkb = wqb + NW;
    unsigned short* wvb = wkb + NW;
    unsigned short* wpb = wvb + NW;
    unsigned short* Qb  = wpb + NW;
    unsigned short* Kb  = Qb  + NX;
    unsigned short* Vtb = Kb  + NX;          // transposed (B,H,HD,T)
    unsigned short* Yb  = Vtb + NX;
    unsigned short* Opart = Yb + NX;         // 32*40 x 64x64 bf16 = 10.5 MB
    float* lpart = (float*)(Opart + (long)32 * NSPLIT_TOT * 4096);

    long n4 = (NX + 4 * NW) / 4;
    cast_all<<<dim3((unsigned)(n4 / 256)), 256, 0, stream>>>(
        x, Wq, Wk, Wv, Wp, xb, wqb, wkb, wvb, wpb);

    gemm_qkv<<<dim3(M_ROWS / 128, C_DIM / 64, 3), 256, 0, stream>>>(
        xb, wqb, wkb, wvb, bq, bk, bv, Qb, Kb, Vtb);

    attn_split<<<dim3(B_BATCH * H_HEADS, NSPLIT_TOT), 256, 0, stream>>>(
        Qb, Kb, Vtb, attn_bias, Opart, lpart, Yb);

    attn_combine<<<dim3(B_BATCH * H_HEADS, 12), 256, 0, stream>>>(
        Opart, lpart, Yb);

    gemm_out_k<<<dim3(M_ROWS / 128, C_DIM / 64), 256, 0, stream>>>(
        Yb, wpb, bp, out);
}